// Round 2
// baseline (749.079 us; speedup 1.0000x reference)
//
#include <hip/hip_runtime.h>
#include <hip/hip_bf16.h>

// ---------------- graph build ----------------
__global__ void k_init_deg(int* deg, int n) {
    int i = blockIdx.x * blockDim.x + threadIdx.x;
    if (i < n) deg[i] = 1;            // self-loop
}

__global__ void k_count(const int* __restrict__ ei, int E, int* deg) {
    int e = blockIdx.x * blockDim.x + threadIdx.x;
    if (e < E) atomicAdd(&deg[ei[E + e]], 1);   // dst row of edge_index
}

// single-block exclusive scan of deg[0..n) -> rowptr[0..n], also copy to wo
__global__ __launch_bounds__(1024) void k_scan(const int* __restrict__ deg,
                                               int* rowptr, int* wo, int n) {
    __shared__ int buf[1024];
    __shared__ int carry;
    if (threadIdx.x == 0) carry = 0;
    __syncthreads();
    for (int base = 0; base < n; base += 1024) {
        int i = base + (int)threadIdx.x;
        int v = (i < n) ? deg[i] : 0;
        buf[threadIdx.x] = v;
        __syncthreads();
        for (int off = 1; off < 1024; off <<= 1) {
            int add = (threadIdx.x >= (unsigned)off) ? buf[threadIdx.x - off] : 0;
            __syncthreads();
            buf[threadIdx.x] += add;
            __syncthreads();
        }
        int incl = buf[threadIdx.x];
        int blocktotal = buf[1023];
        int excl = incl - v + carry;
        if (i < n) { rowptr[i] = excl; wo[i] = excl; }
        __syncthreads();
        if (threadIdx.x == 0) carry += blocktotal;
        __syncthreads();
    }
    if (threadIdx.x == 0) rowptr[n] = carry;
}

__global__ void k_fill(const int* __restrict__ ei, int E, int n,
                       int* wo, int* srcs) {
    int e = blockIdx.x * blockDim.x + threadIdx.x;
    int EP = E + n;
    if (e >= EP) return;
    int s_, d_;
    if (e < E) { s_ = ei[e]; d_ = ei[E + e]; }
    else       { s_ = d_ = e - E; }
    int pos = atomicAdd(&wo[d_], 1);
    srcs[pos] = s_;
}

__global__ void k_dinv(const int* __restrict__ deg, float* dinv, int n) {
    int i = blockIdx.x * blockDim.x + threadIdx.x;
    if (i < n) dinv[i] = rsqrtf((float)deg[i]);
}

// ---------------- GCN (rank-1) ----------------
__global__ void k_sval(const float* __restrict__ x, const float* __restrict__ dinv,
                       const int* __restrict__ rowptr, const int* __restrict__ srcs,
                       float* sval, int n) {
    int d = blockIdx.x * blockDim.x + threadIdx.x;
    if (d >= n) return;
    float sum = 0.f;
    int p1 = rowptr[d + 1];
    for (int p = rowptr[d]; p < p1; ++p) {
        int s = srcs[p];
        sum += x[s] * dinv[s];
    }
    sval[d] = sum * dinv[d];
}

__global__ void k_h0(const float* __restrict__ sval, const float* __restrict__ W0,
                     const float* __restrict__ b0, float* __restrict__ h) {
    int node = blockIdx.x, f = threadIdx.x;
    float v = sval[node] * W0[f] + b0[f];
    h[node * 256 + f] = fmaxf(v, 0.f);
}

// ---------------- GraphNorm ----------------
__global__ void k_zero(float* p, int cnt) {
    int i = blockIdx.x * blockDim.x + threadIdx.x;
    if (i < cnt) p[i] = 0.f;
}

__global__ __launch_bounds__(256) void k_gn_reduce(const float* __restrict__ h,
                                                   float* sums, float* sumsq, int n) {
    int f = threadIdx.x;
    float s = 0.f, q = 0.f;
    for (int r = blockIdx.x; r < n; r += gridDim.x) {
        float v = h[(size_t)r * 256 + f];
        s += v; q += v * v;
    }
    atomicAdd(&sums[f], s);
    atomicAdd(&sumsq[f], q);
}

__global__ void k_gn_apply(float* __restrict__ h, const float* __restrict__ stats,
                           const float* __restrict__ w, const float* __restrict__ b,
                           const float* __restrict__ ms, float ninv) {
    int node = blockIdx.x, f = threadIdx.x;
    float mean = stats[f] * ninv;
    float m2   = stats[256 + f] * ninv;
    float msf  = ms[f];
    float var  = m2 + msf * mean * mean * (msf - 2.0f);
    float scale = w[f] * rsqrtf(var + 1e-5f);
    size_t idx = (size_t)node * 256 + f;
    h[idx] = (h[idx] - msf * mean) * scale + b[f];
}

// ---------------- GEMM: C[M,N] = A[M,K] @ B[K,N] (+bias) ----------------
#define TBM 128
#define TBN 128
#define TBK 16
__global__ __launch_bounds__(256) void k_gemm(const float* __restrict__ A,
                                              const float* __restrict__ B,
                                              float* __restrict__ C,
                                              int M, int N, int K,
                                              const float* __restrict__ bias) {
    __shared__ float As[TBK][TBM];
    __shared__ float Bs[TBK][TBN];
    int bm = blockIdx.x * TBM, bn = blockIdx.y * TBN;
    int tid = threadIdx.x;
    int tx = tid & 15, ty = tid >> 4;
    float acc[8][8] = {};
    for (int k0 = 0; k0 < K; k0 += TBK) {
#pragma unroll
        for (int l = 0; l < 2; ++l) {
            int t = tid + l * 256;           // 0..511 float4 slots, A tile 128x16
            int m  = t >> 2;
            int kq = (t & 3) * 4;
            int row = bm + m;
            float4 v = {0.f, 0.f, 0.f, 0.f};
            if (row < M)
                v = *reinterpret_cast<const float4*>(A + (size_t)row * K + k0 + kq);
            As[kq + 0][m] = v.x; As[kq + 1][m] = v.y;
            As[kq + 2][m] = v.z; As[kq + 3][m] = v.w;
        }
#pragma unroll
        for (int l = 0; l < 2; ++l) {
            int t = tid + l * 256;           // B tile 16x128
            int k  = t >> 5;
            int nq = (t & 31) * 4;
            float4 v = *reinterpret_cast<const float4*>(B + (size_t)(k0 + k) * N + bn + nq);
            *reinterpret_cast<float4*>(&Bs[k][nq]) = v;
        }
        __syncthreads();
#pragma unroll
        for (int k = 0; k < TBK; ++k) {
            float a[8], b[8];
            *reinterpret_cast<float4*>(a)     = *reinterpret_cast<const float4*>(&As[k][ty * 8]);
            *reinterpret_cast<float4*>(a + 4) = *reinterpret_cast<const float4*>(&As[k][ty * 8 + 4]);
            *reinterpret_cast<float4*>(b)     = *reinterpret_cast<const float4*>(&Bs[k][tx * 8]);
            *reinterpret_cast<float4*>(b + 4) = *reinterpret_cast<const float4*>(&Bs[k][tx * 8 + 4]);
#pragma unroll
            for (int i = 0; i < 8; ++i)
#pragma unroll
                for (int j = 0; j < 8; ++j)
                    acc[i][j] = fmaf(a[i], b[j], acc[i][j]);
        }
        __syncthreads();
    }
#pragma unroll
    for (int i = 0; i < 8; ++i) {
        int row = bm + ty * 8 + i;
        if (row >= M) break;
#pragma unroll
        for (int j = 0; j < 8; j += 4) {
            int col = bn + tx * 8 + j;
            float4 v = {acc[i][j], acc[i][j + 1], acc[i][j + 2], acc[i][j + 3]};
            if (bias) {
                v.x += bias[col]; v.y += bias[col + 1];
                v.z += bias[col + 2]; v.w += bias[col + 3];
            }
            *reinterpret_cast<float4*>(C + (size_t)row * N + col) = v;
        }
    }
}

// ---------------- s,t per node (wave per node) ----------------
__global__ __launch_bounds__(256) void k_st(const float* __restrict__ h1,
                                            const float* __restrict__ asrc,
                                            const float* __restrict__ adst,
                                            float* __restrict__ s, float* __restrict__ t,
                                            int n) {
    int wave = threadIdx.x >> 6, lane = threadIdx.x & 63;
    int node = blockIdx.x * 4 + wave;
    if (node >= n) return;
    float4 v = reinterpret_cast<const float4*>(h1 + (size_t)node * 256)[lane];
    int head = lane >> 3;
    int d0 = (lane & 7) * 4;
    const float* as = asrc + head * 32 + d0;
    const float* ad = adst + head * 32 + d0;
    float ps = v.x * as[0] + v.y * as[1] + v.z * as[2] + v.w * as[3];
    float pt = v.x * ad[0] + v.y * ad[1] + v.z * ad[2] + v.w * ad[3];
#pragma unroll
    for (int m = 1; m < 8; m <<= 1) {
        ps += __shfl_xor(ps, m);
        pt += __shfl_xor(pt, m);
    }
    if ((lane & 7) == 0) {
        s[node * 8 + head] = ps;
        t[node * 8 + head] = pt;
    }
}

// ---------------- per-(node,head) softmax over CSR edges ----------------
__global__ void k_softmax(const float* __restrict__ s, const float* __restrict__ t,
                          const int* __restrict__ rowptr, const int* __restrict__ srcs,
                          float* __restrict__ alpha, int n) {
    int gid = blockIdx.x * blockDim.x + threadIdx.x;
    int node = gid >> 3, head = gid & 7;
    if (node >= n) return;
    int p0 = rowptr[node], p1 = rowptr[node + 1];
    float tv = t[node * 8 + head];
    float mx = -1e30f;
    for (int p = p0; p < p1; ++p) {
        float e = s[srcs[p] * 8 + head] + tv;
        e = (e > 0.f) ? e : 0.2f * e;
        alpha[(size_t)p * 8 + head] = e;
        mx = fmaxf(mx, e);
    }
    float den = 0.f;
    for (int p = p0; p < p1; ++p) {
        float w = __expf(alpha[(size_t)p * 8 + head] - mx);
        alpha[(size_t)p * 8 + head] = w;
        den += w;
    }
    float inv = 1.0f / (den + 1e-16f);
    for (int p = p0; p < p1; ++p) alpha[(size_t)p * 8 + head] *= inv;
}

// ---------------- aggregate + bias + relu + residual (wave per node) ----------------
__global__ __launch_bounds__(256) void k_agg(const float* __restrict__ h1,
                                             const float* __restrict__ alpha,
                                             const int* __restrict__ rowptr,
                                             const int* __restrict__ srcs,
                                             float* __restrict__ h,
                                             const float* __restrict__ bias, int n) {
    int wave = threadIdx.x >> 6, lane = threadIdx.x & 63;
    int node = blockIdx.x * 4 + wave;
    if (node >= n) return;
    int p0 = rowptr[node], p1 = rowptr[node + 1];
    int head = lane >> 3;
    float4 acc = {0.f, 0.f, 0.f, 0.f};
    for (int p = p0; p < p1; ++p) {
        float a = alpha[(size_t)p * 8 + head];
        float4 v = reinterpret_cast<const float4*>(h1 + (size_t)srcs[p] * 256)[lane];
        acc.x += a * v.x; acc.y += a * v.y;
        acc.z += a * v.z; acc.w += a * v.w;
    }
    float4 b = {0.f, 0.f, 0.f, 0.f};
    if (bias) b = reinterpret_cast<const float4*>(bias)[lane];
    float4* hp = reinterpret_cast<float4*>(h + (size_t)node * 256) + lane;
    float4 hv = *hp;
    hv.x += fmaxf(acc.x + b.x, 0.f);
    hv.y += fmaxf(acc.y + b.y, 0.f);
    hv.z += fmaxf(acc.z + b.z, 0.f);
    hv.w += fmaxf(acc.w + b.w, 0.f);
    *hp = hv;
}

// ---------------- launch ----------------
extern "C" void kernel_launch(void* const* d_in, const int* in_sizes, int n_in,
                              void* d_out, int out_size, void* d_ws, size_t ws_size,
                              hipStream_t stream) {
    const float* x        = (const float*)d_in[0];
    const float* W0       = (const float*)d_in[1];
    const float* b0       = (const float*)d_in[2];
    const float* gat_lin  = (const float*)d_in[3];
    const float* att_src  = (const float*)d_in[4];
    const float* att_dst  = (const float*)d_in[5];
    const float* gat_bias = (const float*)d_in[6];
    const float* gn_w     = (const float*)d_in[7];
    const float* gn_b     = (const float*)d_in[8];
    const float* gn_ms    = (const float*)d_in[9];
    const float* lin_W    = (const float*)d_in[10];
    const float* lin_b    = (const float*)d_in[11];
    const int*   ei       = (const int*)d_in[12];

    const int n  = in_sizes[0];          // 20000
    const int E  = in_sizes[12] / 2;     // 160000
    const int EP = E + n;                // 180000

    // workspace layout (16B-aligned chunks)
    char* w = (char*)d_ws;
    float* h    = (float*)w; w += (size_t)n * 256 * 4;
    float* h1   = (float*)w; w += (size_t)n * 256 * 4;
    float* alpha= (float*)w; w += (size_t)EP * 8 * 4;
    float* sbuf = (float*)w; w += (size_t)n * 8 * 4;
    float* tbuf = (float*)w; w += (size_t)n * 8 * 4;
    float* sval = (float*)w; w += (size_t)n * 4;
    float* gnstat = (float*)w; w += 512 * 4;
    float* dinv = (float*)w; w += (size_t)n * 4;
    int* deg    = (int*)w;  w += (size_t)n * 4;
    int* rowptr = (int*)w;  w += (size_t)(n + 1) * 4;
    int* wo     = (int*)w;  w += (size_t)n * 4;
    int* srcs   = (int*)w;  w += (size_t)EP * 4;

    const int B256 = 256;
    auto cdiv = [](int a, int b) { return (a + b - 1) / b; };

    // graph build
    k_init_deg<<<cdiv(n, B256), B256, 0, stream>>>(deg, n);
    k_count<<<cdiv(E, B256), B256, 0, stream>>>(ei, E, deg);
    k_scan<<<1, 1024, 0, stream>>>(deg, rowptr, wo, n);
    k_fill<<<cdiv(EP, B256), B256, 0, stream>>>(ei, E, n, wo, srcs);
    k_dinv<<<cdiv(n, B256), B256, 0, stream>>>(deg, dinv, n);

    // GCN layer (rank-1)
    k_sval<<<cdiv(n, B256), B256, 0, stream>>>(x, dinv, rowptr, srcs, sval, n);
    k_h0<<<n, 256, 0, stream>>>(sval, W0, b0, h);

    const float ninv = 1.0f / (float)n;
    const int gx = cdiv(n, TBM);

    for (int i = 0; i < 5; ++i) {
        if (i % 3 == 0) {
            int g = i / 3;
            k_zero<<<2, 256, 0, stream>>>(gnstat, 512);
            k_gn_reduce<<<256, 256, 0, stream>>>(h, gnstat, gnstat + 256, n);
            k_gn_apply<<<n, 256, 0, stream>>>(h, gnstat, gn_w + g * 256,
                                              gn_b + g * 256, gn_ms + g * 256, ninv);
        }
        k_gemm<<<dim3(gx, 2), 256, 0, stream>>>(h, gat_lin + (size_t)i * 256 * 256,
                                                h1, n, 256, 256, nullptr);
        k_st<<<cdiv(n, 4), 256, 0, stream>>>(h1, att_src + i * 256, att_dst + i * 256,
                                             sbuf, tbuf, n);
        k_softmax<<<cdiv(n * 8, B256), B256, 0, stream>>>(sbuf, tbuf, rowptr, srcs,
                                                          alpha, n);
        k_agg<<<cdiv(n, 4), 256, 0, stream>>>(h1, alpha, rowptr, srcs, h,
                                              (i % 3 == 0) ? gat_bias + i * 256 : nullptr,
                                              n);
    }

    // final linear -> d_out
    k_gemm<<<dim3(gx, 1), 256, 0, stream>>>(h, lin_W, (float*)d_out,
                                            n, 128, 256, lin_b);
}

// Round 3
// 490.898 us; speedup vs baseline: 1.5259x; 1.5259x over previous
//
#include <hip/hip_runtime.h>
#include <hip/hip_bf16.h>
#include <stdint.h>

typedef float f32x4 __attribute__((ext_vector_type(4)));
typedef short s16x8 __attribute__((ext_vector_type(8)));

__device__ __forceinline__ float bf2f(unsigned short u) {
    union { unsigned int i; float f; } v; v.i = ((unsigned int)u) << 16; return v.f;
}
__device__ __forceinline__ unsigned short f2bf(float f) {
    union { float f; unsigned int i; } v; v.f = f;
    unsigned int x = v.i;
    return (unsigned short)((x + 0x7fffu + ((x >> 16) & 1u)) >> 16);
}
__device__ __forceinline__ void gload16(const void* g, void* l) {
    __builtin_amdgcn_global_load_lds(
        (const __attribute__((address_space(1))) void*)g,
        (__attribute__((address_space(3))) void*)l, 16, 0, 0);
}

// ---------------- graph build ----------------
__global__ void k_init_deg(int* deg, int n) {
    int i = blockIdx.x * blockDim.x + threadIdx.x;
    if (i < n) deg[i] = 1;            // self-loop
}

__global__ void k_count(const int* __restrict__ ei, int E, int* deg) {
    int e = blockIdx.x * blockDim.x + threadIdx.x;
    if (e < E) atomicAdd(&deg[ei[E + e]], 1);
}

__global__ __launch_bounds__(1024) void k_scan(const int* __restrict__ deg,
                                               int* rowptr, int* wo, int n) {
    __shared__ int buf[1024];
    __shared__ int carry;
    if (threadIdx.x == 0) carry = 0;
    __syncthreads();
    for (int base = 0; base < n; base += 1024) {
        int i = base + (int)threadIdx.x;
        int v = (i < n) ? deg[i] : 0;
        buf[threadIdx.x] = v;
        __syncthreads();
        for (int off = 1; off < 1024; off <<= 1) {
            int add = (threadIdx.x >= (unsigned)off) ? buf[threadIdx.x - off] : 0;
            __syncthreads();
            buf[threadIdx.x] += add;
            __syncthreads();
        }
        int incl = buf[threadIdx.x];
        int blocktotal = buf[1023];
        int excl = incl - v + carry;
        if (i < n) { rowptr[i] = excl; wo[i] = excl; }
        __syncthreads();
        if (threadIdx.x == 0) carry += blocktotal;
        __syncthreads();
    }
    if (threadIdx.x == 0) rowptr[n] = carry;
}

__global__ void k_fill(const int* __restrict__ ei, int E, int n,
                       int* wo, int* srcs) {
    int e = blockIdx.x * blockDim.x + threadIdx.x;
    int EP = E + n;
    if (e >= EP) return;
    int s_, d_;
    if (e < E) { s_ = ei[e]; d_ = ei[E + e]; }
    else       { s_ = d_ = e - E; }
    int pos = atomicAdd(&wo[d_], 1);
    srcs[pos] = s_;
}

__global__ void k_dinv(const int* __restrict__ deg, float* dinv, int n) {
    int i = blockIdx.x * blockDim.x + threadIdx.x;
    if (i < n) dinv[i] = rsqrtf((float)deg[i]);
}

// ---------------- GCN (rank-1) ----------------
__global__ void k_sval(const float* __restrict__ x, const float* __restrict__ dinv,
                       const int* __restrict__ rowptr, const int* __restrict__ srcs,
                       float* sval, int n) {
    int d = blockIdx.x * blockDim.x + threadIdx.x;
    if (d >= n) return;
    float sum = 0.f;
    int p1 = rowptr[d + 1];
    for (int p = rowptr[d]; p < p1; ++p) {
        int s = srcs[p];
        sum += x[s] * dinv[s];
    }
    sval[d] = sum * dinv[d];
}

__global__ void k_h0(const float* __restrict__ sval, const float* __restrict__ W0,
                     const float* __restrict__ b0, float* __restrict__ h,
                     unsigned short* __restrict__ hbf) {
    int node = blockIdx.x, f = threadIdx.x;
    float v = fmaxf(sval[node] * W0[f] + b0[f], 0.f);
    size_t idx = (size_t)node * 256 + f;
    h[idx] = v;
    hbf[idx] = f2bf(v);
}

// ---------------- weight convert + transpose ----------------
// Wt[n*K + k] = bf16(W[k*N + n])
__global__ void k_wconv(const float* __restrict__ W, unsigned short* __restrict__ Wt,
                        int K, int N) {
    int idx = blockIdx.x * blockDim.x + threadIdx.x;
    if (idx >= K * N) return;
    int n = idx / K, k = idx - n * K;
    Wt[idx] = f2bf(W[(size_t)k * N + n]);
}

// ---------------- GraphNorm ----------------
__global__ void k_zero(float* p, int cnt) {
    int i = blockIdx.x * blockDim.x + threadIdx.x;
    if (i < cnt) p[i] = 0.f;
}

__global__ __launch_bounds__(256) void k_gn_reduce(const float* __restrict__ h,
                                                   float* sums, float* sumsq, int n) {
    int f = threadIdx.x;
    float s = 0.f, q = 0.f;
    for (int r = blockIdx.x; r < n; r += gridDim.x) {
        float v = h[(size_t)r * 256 + f];
        s += v; q += v * v;
    }
    atomicAdd(&sums[f], s);
    atomicAdd(&sumsq[f], q);
}

__global__ void k_gn_apply(float* __restrict__ h, unsigned short* __restrict__ hbf,
                           const float* __restrict__ stats,
                           const float* __restrict__ w, const float* __restrict__ b,
                           const float* __restrict__ ms, float ninv) {
    int node = blockIdx.x, f = threadIdx.x;
    float mean = stats[f] * ninv;
    float m2   = stats[256 + f] * ninv;
    float msf  = ms[f];
    float var  = m2 + msf * mean * mean * (msf - 2.0f);
    float scale = w[f] * rsqrtf(var + 1e-5f);
    size_t idx = (size_t)node * 256 + f;
    float v = (h[idx] - msf * mean) * scale + b[f];
    h[idx] = v;
    hbf[idx] = f2bf(v);
}

// ---------------- MFMA GEMM: C[M,N] = A[M,256] @ Bt[N,256]^T ----------------
// A, Bt are bf16 (ushort). A padded so unguarded row reads are safe.
// Output: Cb (bf16, unguarded; caller pads) or Cf (f32, guarded rows) + bias.
#define BM 64
#define BN 64
__global__ __launch_bounds__(256) void k_gemm_mfma(
    const unsigned short* __restrict__ A,
    const unsigned short* __restrict__ Bt,
    unsigned short* __restrict__ Cb,
    float* __restrict__ Cf,
    const float* __restrict__ bias,
    int M, int ldc)
{
    __shared__ unsigned short As[64 * 256];
    __shared__ unsigned short Bs[64 * 256];
    const int tid = threadIdx.x;
    const int bm = blockIdx.x * BM, bn = blockIdx.y * BN;
    const char* ga = (const char*)(A + (size_t)bm * 256);
    const char* gb = (const char*)(Bt + (size_t)bn * 256);
    char* la = (char*)As;
    char* lb = (char*)Bs;
    // stage 32KB A + 32KB B, LDS linear, source pre-swizzled (G4 XOR, 16B gran)
#pragma unroll
    for (int i = 0; i < 8; ++i) {
        int o  = (i * 256 + tid) * 16;
        int so = o ^ (((o >> 9) & 7) << 4);
        gload16(ga + so, la + o);
        gload16(gb + so, lb + o);
    }
    __syncthreads();

    const int lane = tid & 63;
    const int w  = tid >> 6;
    const int wm = (w >> 1) * 32, wn = (w & 1) * 32;
    const int r  = lane & 15, kb = lane >> 4;
    f32x4 acc[2][2] = {};
#pragma unroll
    for (int ks = 0; ks < 8; ++ks) {
        s16x8 af[2], bfr[2];
#pragma unroll
        for (int f = 0; f < 2; ++f) {
            int row = wm + f * 16 + r;
            int c16 = (ks * 4 + kb) ^ (row & 7);
            af[f]  = *(const s16x8*)(la + row * 512 + c16 * 16);
            int col = wn + f * 16 + r;
            int d16 = (ks * 4 + kb) ^ (col & 7);
            bfr[f] = *(const s16x8*)(lb + col * 512 + d16 * 16);
        }
#pragma unroll
        for (int i = 0; i < 2; ++i)
#pragma unroll
            for (int j = 0; j < 2; ++j)
                acc[i][j] = __builtin_amdgcn_mfma_f32_16x16x32_bf16(
                    af[i], bfr[j], acc[i][j], 0, 0, 0);
    }

    const int r4 = (lane >> 4) * 4;
    const int cc = lane & 15;
#pragma unroll
    for (int i = 0; i < 2; ++i) {
#pragma unroll
        for (int j = 0; j < 2; ++j) {
            int col = bn + wn + j * 16 + cc;
            float badd = bias ? bias[col] : 0.f;
#pragma unroll
            for (int q = 0; q < 4; ++q) {
                int row = bm + wm + i * 16 + r4 + q;
                float v = acc[i][j][q] + badd;
                if (Cb) {
                    Cb[(size_t)row * ldc + col] = f2bf(v);
                } else if (row < M) {
                    Cf[(size_t)row * ldc + col] = v;
                }
            }
        }
    }
}

// ---------------- s,t per node (wave per node, bf16 h1) ----------------
__global__ __launch_bounds__(256) void k_st(const unsigned short* __restrict__ h1,
                                            const float* __restrict__ asrc,
                                            const float* __restrict__ adst,
                                            float* __restrict__ s, float* __restrict__ t,
                                            int n) {
    int wave = threadIdx.x >> 6, lane = threadIdx.x & 63;
    int node = blockIdx.x * 4 + wave;
    if (node >= n) return;
    ushort4 v = reinterpret_cast<const ushort4*>(h1 + (size_t)node * 256)[lane];
    float f0 = bf2f(v.x), f1 = bf2f(v.y), f2 = bf2f(v.z), f3 = bf2f(v.w);
    int head = lane >> 3;
    int d0 = (lane & 7) * 4;
    const float* as = asrc + head * 32 + d0;
    const float* ad = adst + head * 32 + d0;
    float ps = f0 * as[0] + f1 * as[1] + f2 * as[2] + f3 * as[3];
    float pt = f0 * ad[0] + f1 * ad[1] + f2 * ad[2] + f3 * ad[3];
#pragma unroll
    for (int m = 1; m < 8; m <<= 1) {
        ps += __shfl_xor(ps, m);
        pt += __shfl_xor(pt, m);
    }
    if ((lane & 7) == 0) {
        s[node * 8 + head] = ps;
        t[node * 8 + head] = pt;
    }
}

// ---------------- per-(node,head) softmax over CSR edges ----------------
__global__ void k_softmax(const float* __restrict__ s, const float* __restrict__ t,
                          const int* __restrict__ rowptr, const int* __restrict__ srcs,
                          float* __restrict__ alpha, int n) {
    int gid = blockIdx.x * blockDim.x + threadIdx.x;
    int node = gid >> 3, head = gid & 7;
    if (node >= n) return;
    int p0 = rowptr[node], p1 = rowptr[node + 1];
    float tv = t[node * 8 + head];
    float mx = -1e30f;
    for (int p = p0; p < p1; ++p) {
        float e = s[srcs[p] * 8 + head] + tv;
        e = (e > 0.f) ? e : 0.2f * e;
        alpha[(size_t)p * 8 + head] = e;
        mx = fmaxf(mx, e);
    }
    float den = 0.f;
    for (int p = p0; p < p1; ++p) {
        float w = __expf(alpha[(size_t)p * 8 + head] - mx);
        alpha[(size_t)p * 8 + head] = w;
        den += w;
    }
    float inv = 1.0f / (den + 1e-16f);
    for (int p = p0; p < p1; ++p) alpha[(size_t)p * 8 + head] *= inv;
}

// ---------------- aggregate + bias + relu + residual ----------------
__global__ __launch_bounds__(256) void k_agg(const unsigned short* __restrict__ h1,
                                             const float* __restrict__ alpha,
                                             const int* __restrict__ rowptr,
                                             const int* __restrict__ srcs,
                                             float* __restrict__ h,
                                             unsigned short* __restrict__ hbf,
                                             const float* __restrict__ bias, int n) {
    int wave = threadIdx.x >> 6, lane = threadIdx.x & 63;
    int node = blockIdx.x * 4 + wave;
    if (node >= n) return;
    int p0 = rowptr[node], p1 = rowptr[node + 1];
    int head = lane >> 3;
    float a0 = 0.f, a1 = 0.f, a2 = 0.f, a3 = 0.f;
    for (int p = p0; p < p1; ++p) {
        float al = alpha[(size_t)p * 8 + head];
        ushort4 v = reinterpret_cast<const ushort4*>(h1 + (size_t)srcs[p] * 256)[lane];
        a0 += al * bf2f(v.x); a1 += al * bf2f(v.y);
        a2 += al * bf2f(v.z); a3 += al * bf2f(v.w);
    }
    float b0_ = 0.f, b1_ = 0.f, b2_ = 0.f, b3_ = 0.f;
    if (bias) {
        float4 bb = reinterpret_cast<const float4*>(bias)[lane];
        b0_ = bb.x; b1_ = bb.y; b2_ = bb.z; b3_ = bb.w;
    }
    size_t base = (size_t)node * 256 + lane * 4;
    float4 hv = *reinterpret_cast<float4*>(h + base);
    hv.x += fmaxf(a0 + b0_, 0.f);
    hv.y += fmaxf(a1 + b1_, 0.f);
    hv.z += fmaxf(a2 + b2_, 0.f);
    hv.w += fmaxf(a3 + b3_, 0.f);
    *reinterpret_cast<float4*>(h + base) = hv;
    ushort4 o;
    o.x = f2bf(hv.x); o.y = f2bf(hv.y); o.z = f2bf(hv.z); o.w = f2bf(hv.w);
    *reinterpret_cast<ushort4*>(hbf + base) = o;
}

// ---------------- launch ----------------
extern "C" void kernel_launch(void* const* d_in, const int* in_sizes, int n_in,
                              void* d_out, int out_size, void* d_ws, size_t ws_size,
                              hipStream_t stream) {
    const float* x        = (const float*)d_in[0];
    const float* W0       = (const float*)d_in[1];
    const float* b0       = (const float*)d_in[2];
    const float* gat_lin  = (const float*)d_in[3];
    const float* att_src  = (const float*)d_in[4];
    const float* att_dst  = (const float*)d_in[5];
    const float* gat_bias = (const float*)d_in[6];
    const float* gn_w     = (const float*)d_in[7];
    const float* gn_b     = (const float*)d_in[8];
    const float* gn_ms    = (const float*)d_in[9];
    const float* lin_W    = (const float*)d_in[10];
    const float* lin_b    = (const float*)d_in[11];
    const int*   ei       = (const int*)d_in[12];

    const int n  = in_sizes[0];          // 20000
    const int E  = in_sizes[12] / 2;     // 160000
    const int EP = E + n;                // 180000
    const int Mpad = ((n + BM - 1) / BM) * BM;   // 20032

    // workspace layout (16B-aligned chunks)
    char* w = (char*)d_ws;
    float* h    = (float*)w;          w += (size_t)n * 256 * 4;
    unsigned short* hbf = (unsigned short*)w; w += (size_t)Mpad * 256 * 2;
    unsigned short* h1  = (unsigned short*)w; w += (size_t)Mpad * 256 * 2;
    float* alpha= (float*)w;          w += (size_t)EP * 8 * 4;
    float* sbuf = (float*)w;          w += (size_t)n * 8 * 4;
    float* tbuf = (float*)w;          w += (size_t)n * 8 * 4;
    unsigned short* Wt = (unsigned short*)w; w += (size_t)5 * 256 * 256 * 2;
    unsigned short* lt = (unsigned short*)w; w += (size_t)128 * 256 * 2;
    float* sval = (float*)w;          w += (size_t)n * 4;
    float* gnstat = (float*)w;        w += 512 * 4;
    float* dinv = (float*)w;          w += (size_t)n * 4;
    int* deg    = (int*)w;            w += (size_t)n * 4;
    int* rowptr = (int*)w;            w += ((size_t)(n + 1) * 4 + 15) / 16 * 16;
    int* wo     = (int*)w;            w += (size_t)n * 4;
    int* srcs   = (int*)w;            w += (size_t)EP * 4;

    const int B256 = 256;
    auto cdiv = [](int a, int b) { return (a + b - 1) / b; };

    // weight conversion (once per launch)
    for (int i = 0; i < 5; ++i)
        k_wconv<<<cdiv(256 * 256, B256), B256, 0, stream>>>(
            gat_lin + (size_t)i * 256 * 256, Wt + (size_t)i * 256 * 256, 256, 256);
    k_wconv<<<cdiv(256 * 128, B256), B256, 0, stream>>>(lin_W, lt, 256, 128);

    // graph build
    k_init_deg<<<cdiv(n, B256), B256, 0, stream>>>(deg, n);
    k_count<<<cdiv(E, B256), B256, 0, stream>>>(ei, E, deg);
    k_scan<<<1, 1024, 0, stream>>>(deg, rowptr, wo, n);
    k_fill<<<cdiv(EP, B256), B256, 0, stream>>>(ei, E, n, wo, srcs);
    k_dinv<<<cdiv(n, B256), B256, 0, stream>>>(deg, dinv, n);

    // GCN layer (rank-1)
    k_sval<<<cdiv(n, B256), B256, 0, stream>>>(x, dinv, rowptr, srcs, sval, n);
    k_h0<<<n, 256, 0, stream>>>(sval, W0, b0, h, hbf);

    const float ninv = 1.0f / (float)n;
    const int gx = Mpad / BM;   // 313

    for (int i = 0; i < 5; ++i) {
        if (i % 3 == 0) {
            int g = i / 3;
            k_zero<<<2, 256, 0, stream>>>(gnstat, 512);
            k_gn_reduce<<<256, 256, 0, stream>>>(h, gnstat, gnstat + 256, n);
            k_gn_apply<<<n, 256, 0, stream>>>(h, hbf, gnstat, gn_w + g * 256,
                                              gn_b + g * 256, gn_ms + g * 256, ninv);
        }
        k_gemm_mfma<<<dim3(gx, 4), 256, 0, stream>>>(
            hbf, Wt + (size_t)i * 256 * 256, h1, nullptr, nullptr, n, 256);
        k_st<<<cdiv(n, 4), 256, 0, stream>>>(h1, att_src + i * 256, att_dst + i * 256,
                                             sbuf, tbuf, n);
        k_softmax<<<cdiv(n * 8, B256), B256, 0, stream>>>(sbuf, tbuf, rowptr, srcs,
                                                          alpha, n);
        k_agg<<<cdiv(n, 4), 256, 0, stream>>>(h1, alpha, rowptr, srcs, h, hbf,
                                              (i % 3 == 0) ? gat_bias + i * 256 : nullptr,
                                              n);
    }

    // final linear -> d_out (fp32, guarded)
    k_gemm_mfma<<<dim3(gx, 2), 256, 0, stream>>>(
        hbf, lt, nullptr, (float*)d_out, lin_b, n, 128);
}